// Round 5
// baseline (278.077 us; speedup 1.0000x reference)
//
#include <hip/hip_runtime.h>
#include <hip/hip_bf16.h>
#include <cstdint>
#include <cstddef>

typedef __bf16 bf16_t;
typedef __bf16 bf16x8 __attribute__((ext_vector_type(8)));
typedef __bf16 bf16x4 __attribute__((ext_vector_type(4)));
typedef float  f32x4  __attribute__((ext_vector_type(4)));

#define KDIM 1024
#define NT   16        // K-tiles (BK=64) per 256x256 output tile

// ---------------------------------------------------------------------------
// Kernel 1 (fused prep): blocks [0,Bn): softmax(mod)+1 scale of x -> bf16 A.
//                        blocks [Bn, ...): fp32->bf16 cast of W.
// (HBM-bound at ~6.3 TB/s roofline: 104 MB moved in ~17 us -- leave alone.)
// ---------------------------------------------------------------------------
__global__ void prep_kernel(const float* __restrict__ x,
                            const float* __restrict__ mod,
                            const float* __restrict__ W,
                            bf16_t* __restrict__ a,
                            bf16_t* __restrict__ Wb,
                            int D, int Bn) {
  if ((int)blockIdx.x >= Bn) {
    const size_t i = (((size_t)blockIdx.x - Bn) * blockDim.x + threadIdx.x) * 8;
    float4 u = *(const float4*)(W + i);
    float4 v = *(const float4*)(W + i + 4);
    bf16x8 o;
    o[0] = (bf16_t)u.x; o[1] = (bf16_t)u.y; o[2] = (bf16_t)u.z; o[3] = (bf16_t)u.w;
    o[4] = (bf16_t)v.x; o[5] = (bf16_t)v.y; o[6] = (bf16_t)v.z; o[7] = (bf16_t)v.w;
    *(bf16x8*)(Wb + i) = o;
    return;
  }

  const int b = blockIdx.x;
  const int t = threadIdx.x;
  const size_t row = (size_t)b * D;

  float4 mv = ((const float4*)(mod + row))[t];
  float mx = fmaxf(fmaxf(mv.x, mv.y), fmaxf(mv.z, mv.w));
#pragma unroll
  for (int o = 32; o > 0; o >>= 1) mx = fmaxf(mx, __shfl_xor(mx, o));

  __shared__ float redmax[4];
  __shared__ float redsum[4];
  const int wave = t >> 6, lane = t & 63;
  if (lane == 0) redmax[wave] = mx;
  __syncthreads();
  mx = fmaxf(fmaxf(redmax[0], redmax[1]), fmaxf(redmax[2], redmax[3]));

  float4 e;
  e.x = __expf(mv.x - mx); e.y = __expf(mv.y - mx);
  e.z = __expf(mv.z - mx); e.w = __expf(mv.w - mx);
  float s = (e.x + e.y) + (e.z + e.w);
#pragma unroll
  for (int o = 32; o > 0; o >>= 1) s += __shfl_xor(s, o);
  if (lane == 0) redsum[wave] = s;
  __syncthreads();
  s = (redsum[0] + redsum[1]) + (redsum[2] + redsum[3]);

  const float inv = 1.0f / s;
  float4 xv = ((const float4*)(x + row))[t];
  bf16x4 o4;
  o4[0] = (bf16_t)((e.x * inv + 1.0f) * xv.x);
  o4[1] = (bf16_t)((e.y * inv + 1.0f) * xv.y);
  o4[2] = (bf16_t)((e.z * inv + 1.0f) * xv.z);
  o4[3] = (bf16_t)((e.w * inv + 1.0f) * xv.w);
  *((bf16x4*)(a + row) + t) = o4;
}

// ---------------------------------------------------------------------------
// Kernel 2: 256x256-tile bf16 GEMM (B^T input), barrier-minimal.
//   C[m][n] = sum_k A[m][k] * B[n][k];  A:(M,K) bf16, B:(N,K) bf16, C fp32.
// 8 waves (2M x 4N), per-wave output 128x64.
// - A staged in LDS (double-buffered, 2 x 32 KB), XOR swizzle c8^=(row&7) on
//   global source at stage time + on ds_read column (conflict-free).
// - B is NOT staged: per-wave B-fragments loaded DIRECTLY global->VGPR
//   (8 x dwordx4/tile), double-buffered in registers, issued 2 tiles ahead.
//   Twin waves (wave, wave+4) read identical B-frags -> L1 hits; W panel is
//   L2-hot. Removes 96 KB/tile of LDS traffic + the 12-read prime burst.
// - ONE s_barrier + ONE counted vmcnt per tile (double buffer makes intra-
//   tile barriers unnecessary). Compiler interleaves ds_read/MFMA with its
//   own counted lgkmcnt; waves drift within a tile -> cross-wave overlap.
// vmcnt queue at tile-t end (in-order): [B(t+2)old:8][A(t+1):4][B(t+2):8]
//   -> vmcnt(8) retires old-B + A(t+1), leaves B(t+2) in flight. Never 0
//   in steady state; 0 only for the last two tiles.
// ---------------------------------------------------------------------------
__global__ __launch_bounds__(512, 2) void gemm256_kernel(
    const bf16_t* __restrict__ A, const bf16_t* __restrict__ B,
    float* __restrict__ C, int M, int N) {
  __shared__ __align__(16) bf16_t As[2][16384];   // 64 KiB total

  const int tid  = threadIdx.x;
  const int wave = tid >> 6;
  const int lane = tid & 63;
  const int quad = lane >> 4;
  const int l16  = lane & 15;
  const int wm   = wave >> 2;      // 0..1 -> 128 M-rows
  const int wn   = wave & 3;       // 0..3 -> 64 N-cols

  // XCD-aware bijective swizzle (nwg = 512, % 8 == 0); m-major chunks:
  // per-XCD chunk = 4 m-rows x 16 n -> A panels (2 MB) L2-resident.
  const int nwg = gridDim.x;
  int flat = blockIdx.x;
  flat = (flat & 7) * (nwg >> 3) + (flat >> 3);
  const int ntiles = N >> 8;
  const int m0 = (flat / ntiles) << 8;
  const int n0 = (flat % ntiles) << 8;

  // A staging: slot s = i*512 + tid (i=0..3), row = s>>3, lds_c8 = tid&7,
  // global c8 = (tid&7) ^ (row&7)  (i*64 doesn't change row&7).
  const int trow = tid >> 3;                       // 0..63
  const int colg = (tid & 7) ^ (trow & 7);
  const bf16_t* aSrc = A + (size_t)(m0 + trow) * KDIM + colg * 8;
  const int ldsW = wave * 512;                     // wave-uniform dest (elems)

#define GLDS(src_, dst_) __builtin_amdgcn_global_load_lds( \
      (const __attribute__((address_space(1))) void*)(src_), \
      (__attribute__((address_space(3))) void*)(dst_), 16, 0, 0)

  // Stage A K-tile t_ into As[t_&1]: 4 GLDS per wave, instr i covers rows
  // [i*64, i*64+64) of the 256-row tile.
#define STAGE_A(t_) do { \
      if ((t_) < NT) { \
        _Pragma("unroll") \
        for (int i_ = 0; i_ < 4; ++i_) { \
          GLDS(aSrc + (size_t)(i_ * 64) * KDIM + (t_) * 64, \
               &As[(t_) & 1][i_ * 4096 + ldsW]); \
        } \
      } \
    } while (0)

  // Per-wave B fragment base pointers: row nb = n0 + wn*64 + j*16 + l16,
  // frag (j, kt) = 16 B at bP[j] + t*64 + kt*32.
  const bf16_t* bP[4];
#pragma unroll
  for (int j = 0; j < 4; ++j)
    bP[j] = B + (size_t)(n0 + wn * 64 + j * 16 + l16) * KDIM + quad * 8;

#define PRELOAD_B(DST_, t_) do { \
      if ((t_) < NT) { \
        _Pragma("unroll") \
        for (int j_ = 0; j_ < 4; ++j_) { \
          DST_[j_][0] = *(const bf16x8*)(bP[j_] + (t_) * 64); \
          DST_[j_][1] = *(const bf16x8*)(bP[j_] + (t_) * 64 + 32); \
        } \
      } \
    } while (0)

  f32x4 acc[8][4];
#pragma unroll
  for (int i = 0; i < 8; ++i)
#pragma unroll
    for (int j = 0; j < 4; ++j) acc[i][j] = (f32x4){0.f, 0.f, 0.f, 0.f};

  const int aBase = (wm * 128 + l16) * 64;
  const int c0 = ((quad)     ^ (l16 & 7)) * 8;     // kt=0 swizzled column
  const int c1 = ((4 + quad) ^ (l16 & 7)) * 8;     // kt=1

  bf16x8 bX[4][2], bY[4][2];   // 2-deep register B buffers (static names)

  // Prologue: A(0) GLDS (4), B(0)->bX (8), B(1)->bY (8).
  // vmcnt(8) retires A(0)+B(0), leaves B(1) in flight.
  STAGE_A(0);
  PRELOAD_B(bX, 0);
  PRELOAD_B(bY, 1);
  asm volatile("s_waitcnt vmcnt(8)" ::: "memory");
  __builtin_amdgcn_s_barrier();

#define MFMA16(q_, af_, BF_) do { \
      _Pragma("unroll") \
      for (int i_ = 0; i_ < 2; ++i_) \
        _Pragma("unroll") \
        for (int j_ = 0; j_ < 4; ++j_) { \
          acc[(q_) * 2 + i_][j_] = __builtin_amdgcn_mfma_f32_16x16x32_bf16( \
              af_[i_][0], BF_[j_][0], acc[(q_) * 2 + i_][j_], 0, 0, 0); \
          acc[(q_) * 2 + i_][j_] = __builtin_amdgcn_mfma_f32_16x16x32_bf16( \
              af_[i_][1], BF_[j_][1], acc[(q_) * 2 + i_][j_], 0, 0, 0); \
        } \
    } while (0)

  // One tile: stage A(t+1) early; 4 quadrants of {4 ds_read + 16 MFMA}
  // (compiler-scheduled, counted lgkmcnt); preload B(t+2) after last use of
  // BCUR regs (WAR orders it); single counted vmcnt + single barrier.
#define TILE(t_, BCUR_, BNXT_) do { \
      const bf16_t* At = As[(t_) & 1]; \
      STAGE_A((t_) + 1); \
      _Pragma("unroll") \
      for (int q_ = 0; q_ < 4; ++q_) { \
        bf16x8 af_[2][2]; \
        _Pragma("unroll") \
        for (int i_ = 0; i_ < 2; ++i_) { \
          af_[i_][0] = *(const bf16x8*)(At + aBase + (q_ * 32 + i_ * 16) * 64 + c0); \
          af_[i_][1] = *(const bf16x8*)(At + aBase + (q_ * 32 + i_ * 16) * 64 + c1); \
        } \
        __builtin_amdgcn_s_setprio(1); \
        MFMA16(q_, af_, BCUR_); \
        __builtin_amdgcn_s_setprio(0); \
      } \
      PRELOAD_B(BNXT_, (t_) + 2); \
      if ((t_) < NT - 2) { asm volatile("s_waitcnt vmcnt(8)" ::: "memory"); } \
      else               { asm volatile("s_waitcnt vmcnt(0)" ::: "memory"); } \
      __builtin_amdgcn_s_barrier(); \
    } while (0)

#pragma unroll 1
  for (int tt = 0; tt < NT; tt += 2) {
    TILE(tt,     bX, bX);   // even tiles use/refill bX
    TILE(tt + 1, bY, bY);   // odd tiles use/refill bY
  }

  // Epilogue: C/D 16x16 layout: col = l16, row = quad*4 + reg.
#pragma unroll
  for (int ri = 0; ri < 8; ++ri) {
    const int mg = m0 + wm * 128 + ri * 16 + quad * 4;
#pragma unroll
    for (int j = 0; j < 4; ++j) {
      const int ng = n0 + wn * 64 + j * 16 + l16;
#pragma unroll
      for (int r = 0; r < 4; ++r)
        C[(size_t)(mg + r) * N + ng] = acc[ri][j][r];
    }
  }
}

// ---------------------------------------------------------------------------
extern "C" void kernel_launch(void* const* d_in, const int* in_sizes, int n_in,
                              void* d_out, int out_size, void* d_ws, size_t ws_size,
                              hipStream_t stream) {
  const float* x   = (const float*)d_in[0];
  const float* mod = (const float*)d_in[1];
  const float* W   = (const float*)d_in[2];
  float* out = (float*)d_out;

  const int D = 1024;
  const int Bn = in_sizes[0] / D;  // 8192
  const int Cn = in_sizes[2] / D;  // 4096

  bf16_t* a  = (bf16_t*)d_ws;                                             // B*D bf16
  bf16_t* Wb = (bf16_t*)((char*)d_ws + (size_t)Bn * D * sizeof(bf16_t));  // C*D bf16

  const int castBlocks = (Cn * D) / (256 * 8);   // 2048
  prep_kernel<<<Bn + castBlocks, 256, 0, stream>>>(x, mod, W, a, Wb, D, Bn);

  const int nwg = (Bn / 256) * (Cn / 256);  // 32*16 = 512, % 8 == 0
  gemm256_kernel<<<nwg, 512, 0, stream>>>(a, Wb, out, Bn, Cn);
}